// Round 4
// baseline (87.451 us; speedup 1.0000x reference)
//
#include <hip/hip_runtime.h>
#include <math.h>

// OscillatorBank: B=16, T=500, H=100, HOP=64 -> out [B, T*HOP] f32.
// phase(b, t*64+j, h) = 2pi*( frac(64*S_{t-1}[b,h]) + (j+1)*w_rev[b,t,h] ),
//   w_rev = h^(1+stretch)*f0 / SR (cycles/sample), S = prefix sum of w_rev over t.
// R4: scan stores float4 (w, base, c, 0) per (b,t,h); synth reads rows at
// wave-uniform addresses -> compiler emits s_load (SMEM pipe), inner loop is
// pure VALU: v_fmac + v_sin_f32 (revolutions). No LDS anywhere.

#define OB_B 16
#define OB_T 500
#define OB_H 100
#define OB_HOP 64

constexpr double SR_D = 44100.0;

// Kernel 1: one wave per (b,h). Lane l handles t in [8l, 8l+8).
// Computes w_rev in double (exp2 with wave-uniform log2(h)), wave shfl-scan of
// chunk sums, writes float4(w_rev, frac(64*S_{t-1}), c, 0) at [bt*H + h].
__global__ void __launch_bounds__(256)
ob_scan_fused(const float* __restrict__ f0,
              const float* __restrict__ loud,
              const float* __restrict__ amps,
              const float* __restrict__ stretch,
              float4* __restrict__ wbc)
{
    int wave = threadIdx.x >> 6;
    int lane = threadIdx.x & 63;
    int bh   = blockIdx.x * 4 + wave;      // 0..1599
    int b = bh / OB_H, h = bh % OB_H;
    double L = log2((double)(h + 1));      // wave-uniform
    const float* f0b = f0      + b * OB_T;
    const float* stb = stretch + b * OB_T;
    const float* ldb = loud    + b * OB_T;

    double w[8];
    double csum = 0.0;
    int t0 = lane * 8;
    #pragma unroll
    for (int k = 0; k < 8; ++k) {
        int t = t0 + k;
        double wv = 0.0;
        if (t < OB_T)
            wv = exp2((1.0 + (double)stb[t]) * L) * (double)f0b[t] * (1.0 / SR_D);
        w[k] = wv;
        csum += wv;
    }
    // inclusive wave scan of chunk sums (double shuffles)
    double incl = csum;
    #pragma unroll
    for (int off = 1; off < 64; off <<= 1) {
        double up = __shfl_up(incl, (unsigned)off, 64);
        if (lane >= off) incl += up;
    }
    double S = incl - csum;                // exclusive prefix: sum of w for t < t0
    #pragma unroll
    for (int k = 0; k < 8; ++k) {
        int t = t0 + k;
        if (t < OB_T) {
            double ph = 64.0 * S;
            ph -= trunc(ph);               // frac, revolutions
            int bt = b * OB_T + t;
            float wf = (float)w[k];
            // Nyquist mask: harm > 22050 Hz <=> w_rev > 0.5
            float c  = (wf > 0.5f) ? 0.0f
                       : ldb[t] * amps[(size_t)bt * OB_H + h] * (1.0f / OB_H);
            wbc[(size_t)bt * OB_H + h] = make_float4(wf, (float)ph, c, 0.0f);
            S += w[k];
        }
    }
}

// Kernel 2: 256 threads = 4 waves = 4 hops; lane j = sample in hop.
// Row reads are wave-uniform -> SMEM (s_load_dwordx4); inner loop pure VALU.
__global__ void __launch_bounds__(256)
ob_synth(const float4* __restrict__ wbc,
         float* __restrict__ out)
{
    int wave = threadIdx.x >> 6;
    int lane = threadIdx.x & 63;
    int bt   = __builtin_amdgcn_readfirstlane(blockIdx.x * 4 + wave); // b*T + t, forced uniform
    const float4* __restrict__ row = wbc + (size_t)bt * OB_H;

    float jf  = (float)(lane + 1);
    float acc = 0.0f;
    #pragma unroll 10
    for (int h = 0; h < OB_H; ++h) {
        float4 q = row[h];                 // uniform addr -> s_load_dwordx4
        acc += q.z * __builtin_amdgcn_sinf(q.y + jf * q.x);  // v_sin_f32, revolutions
    }
    out[(size_t)bt * OB_HOP + lane] = acc; // out[b, t*64 + j]
}

extern "C" void kernel_launch(void* const* d_in, const int* in_sizes, int n_in,
                              void* d_out, int out_size, void* d_ws, size_t ws_size,
                              hipStream_t stream)
{
    const float* f0      = (const float*)d_in[0];
    const float* loud    = (const float*)d_in[1];
    const float* amps    = (const float*)d_in[2];
    const float* stretch = (const float*)d_in[3];

    float4* wbc = (float4*)d_ws;           // 800000 * 16B = 12.8 MB
    float*  out = (float*)d_out;

    ob_scan_fused<<<(OB_B * OB_H) / 4, 256, 0, stream>>>(f0, loud, amps, stretch, wbc);
    ob_synth<<<(OB_B * OB_T) / 4, 256, 0, stream>>>(wbc, out);
}